// Round 6
// baseline (372.898 us; speedup 1.0000x reference)
//
#include <hip/hip_runtime.h>

// ---------------------------------------------------------------------------
// CrossAttention (trinity mask) on MI355X.
// B=4, N=2048 (IMG=1536 in 3 chunks of 512, TXT=512), C=1024, H=16, d=64.
// R6: QKV projections fused into one 1536-block kernel with bijective
//     XCD-chunked swizzle (A-panel + weight L2 residency); out-proj swizzled
//     too. Attention moves to 8-wave blocks (128 q-rows, 3 blocks/CU) with
//     V01 prefetch before softmax and in-place masking.
// fp16 fragments + f32 accumulation (bf16 would blow absmax through the
// 4-matmul chain; fp16 is same MFMA rate on gfx950).
// ---------------------------------------------------------------------------

typedef _Float16 h16;
typedef _Float16 f16x8 __attribute__((ext_vector_type(8)));
typedef __fp16 fp16v2 __attribute__((ext_vector_type(2)));
typedef float f32x4 __attribute__((ext_vector_type(4)));

#define BATCH 4
#define NTOK  2048
#define CDIM  1024
#define NHEAD 16
#define HDIM  64
#define IMGTOK 1536
#define MROWS (BATCH * NTOK)   // 8192
#define QSCALE 0.18033688011112042f   /* 0.125 * log2(e) */

__device__ __forceinline__ void gload_lds16(const void* g, void* l) {
  __builtin_amdgcn_global_load_lds(
      (const __attribute__((address_space(1))) unsigned int*)g,
      (__attribute__((address_space(3))) unsigned int*)l, 16, 0, 0);
}

// ---------------------------------------------------------------------------
// f32 -> fp16 elementwise convert, 8 elems/thread
__global__ __launch_bounds__(256)
void cvt_f16(const float* __restrict__ s, h16* __restrict__ d) {
  size_t i = ((size_t)blockIdx.x * 256 + threadIdx.x) * 8;
  float4 a = *(const float4*)(s + i);
  float4 b = *(const float4*)(s + i + 4);
  f16x8 o;
  o[0] = (h16)a.x; o[1] = (h16)a.y; o[2] = (h16)a.z; o[3] = (h16)a.w;
  o[4] = (h16)b.x; o[5] = (h16)b.y; o[6] = (h16)b.z; o[7] = (h16)b.w;
  *(f16x8*)(d + i) = o;
}

// ---------------------------------------------------------------------------
// W [K=1024][N=1024] f32  ->  WT [N][K] fp16   (4 weights via blockIdx.z)
__global__ __launch_bounds__(256)
void wtrans(const float* __restrict__ W0, const float* __restrict__ W1,
            const float* __restrict__ W2, const float* __restrict__ W3,
            h16* __restrict__ T0, h16* __restrict__ T1,
            h16* __restrict__ T2, h16* __restrict__ T3) {
  const float* W; h16* T;
  switch (blockIdx.z) {
    case 0: W = W0; T = T0; break;
    case 1: W = W1; T = T1; break;
    case 2: W = W2; T = T2; break;
    default: W = W3; T = T3; break;
  }
  __shared__ float t[32][33];
  const int n0 = blockIdx.x * 32, k0 = blockIdx.y * 32;
  const int tx = threadIdx.x, ty = threadIdx.y;  // (32,8)
#pragma unroll
  for (int i = 0; i < 4; i++)
    t[ty + 8 * i][tx] = W[(size_t)(k0 + ty + 8 * i) * CDIM + n0 + tx];
  __syncthreads();
#pragma unroll
  for (int i = 0; i < 4; i++)
    T[(size_t)(n0 + ty + 8 * i) * CDIM + k0 + tx] = (h16)t[tx][ty + 8 * i];
}

// ---------------------------------------------------------------------------
// Shared GEMM body pieces: 128x128 tile, BK=32, 4 waves, 3-buffer pipeline
// (48KB), counted vmcnt(4), one barrier per K-step, chunk-XOR LDS swizzle.

// Fused QKV projection: 1536 blocks, XCD-chunked bijective swizzle.
// which=0: Qh heads layout * QSCALE; which=1: Kh heads; which=2: VTh headsT.
__global__ __launch_bounds__(256, 3)
void gemm_qkv(const h16* __restrict__ qb, const h16* __restrict__ kvb,
              const h16* __restrict__ wqt, const h16* __restrict__ wkt,
              const h16* __restrict__ wvt,
              const float* __restrict__ bq, const float* __restrict__ bk,
              const float* __restrict__ bv,
              h16* __restrict__ Qh, h16* __restrict__ Kh,
              h16* __restrict__ VTh) {
  __shared__ __attribute__((aligned(16))) h16 smem[3 * 8192];
  const int id = blockIdx.x;                 // 1536 = 8 XCD * 192
  const int gid = (id & 7) * 192 + (id >> 3);
  const int which = gid >> 9;                // 0..2
  const int lid = gid & 511;
  const int m0 = (lid >> 3) * 128;
  const int n0 = (lid & 7) * 128;
  const h16* X  = (which == 0) ? qb : kvb;
  const h16* WT = (which == 0) ? wqt : ((which == 1) ? wkt : wvt);
  const float* bias = (which == 0) ? bq : ((which == 1) ? bk : bv);

  const int tid = threadIdx.x;
  const int lane = tid & 63;
  const int w = tid >> 6;
  const int wr = w >> 1, wc = w & 1;
  const int l15 = lane & 15, lhi = lane >> 4;

  f32x4 acc[4][4] = {};

  const int sr = tid >> 2;
  const int pc = tid & 3;
  const int lc = pc ^ ((sr >> 1) & 3);
  const h16* gA0 = X + (size_t)(m0 + sr) * CDIM + lc * 8;
  const h16* gA1 = gA0 + (size_t)64 * CDIM;
  const h16* gB0 = WT + (size_t)(n0 + sr) * CDIM + lc * 8;
  const h16* gB1 = gB0 + (size_t)64 * CDIM;

#define GSTAGE(bi, kt)                                      \
  do {                                                      \
    h16* A_ = smem + (bi) * 8192;                           \
    h16* B_ = A_ + 4096;                                    \
    gload_lds16(gA0 + (kt) * 32, A_ + tid * 8);             \
    gload_lds16(gA1 + (kt) * 32, A_ + (256 + tid) * 8);     \
    gload_lds16(gB0 + (kt) * 32, B_ + tid * 8);             \
    gload_lds16(gB1 + (kt) * 32, B_ + (256 + tid) * 8);     \
  } while (0)

  const int NT = CDIM / 32;
  GSTAGE(0, 0);
  GSTAGE(1, 1);
  const int rswz = (l15 >> 1) & 3;

  int rb = 0, sb = 2;
  for (int kt = 0; kt < NT; ++kt) {
    if (kt + 1 < NT) asm volatile("s_waitcnt vmcnt(4)" ::: "memory");
    else             asm volatile("s_waitcnt vmcnt(0)" ::: "memory");
    __builtin_amdgcn_s_barrier();
    if (kt + 2 < NT) { GSTAGE(sb, kt + 2); sb = (sb == 2) ? 0 : sb + 1; }
    const h16* A_ = smem + rb * 8192;
    const h16* B_ = A_ + 4096;
    rb = (rb == 2) ? 0 : rb + 1;
    f16x8 a[4], bb[4];
#pragma unroll
    for (int i = 0; i < 4; i++)
      a[i] = *(const f16x8*)(A_ + (wr * 64 + i * 16 + l15) * 32 + (lhi ^ rswz) * 8);
#pragma unroll
    for (int i = 0; i < 4; i++)
      bb[i] = *(const f16x8*)(B_ + (wc * 64 + i * 16 + l15) * 32 + (lhi ^ rswz) * 8);
    __builtin_amdgcn_s_setprio(1);
#pragma unroll
    for (int i = 0; i < 4; i++)
#pragma unroll
      for (int j = 0; j < 4; j++)
        acc[i][j] = __builtin_amdgcn_mfma_f32_16x16x32_f16(a[i], bb[j], acc[i][j], 0, 0, 0);
    __builtin_amdgcn_s_setprio(0);
  }
#undef GSTAGE

  if (which == 2) {
    // transpose epilogue -> VTh [B,H,64,N], coalesced 256B rows
    __builtin_amdgcn_s_barrier();
    h16* T = smem;  // [128][128], chunk = (grL>>3) ^ (gcL&15)
#pragma unroll
    for (int j = 0; j < 4; j++) {
      const int gcL = wc * 64 + j * 16 + l15;
      const float bval = bias[n0 + gcL];
#pragma unroll
      for (int i = 0; i < 4; i++) {
#pragma unroll
        for (int r = 0; r < 4; r++) {
          const int grL = wr * 64 + i * 16 + lhi * 4 + r;
          const int ch = (grL >> 3) ^ (gcL & 15);
          T[gcL * 128 + ch * 8 + (grL & 7)] = (h16)(acc[i][j][r] + bval);
        }
      }
    }
    __builtin_amdgcn_s_barrier();
    const int bsel = m0 >> 11;
    const int nbase = m0 & (NTOK - 1);
#pragma unroll
    for (int pass = 0; pass < 8; ++pass) {
      const int rowL = pass * 16 + (tid >> 4);
      const int c = tid & 15;
      const int gc = n0 + rowL;
      const int hh = gc >> 6, dd = gc & 63;
      f16x8 v = *(const f16x8*)(T + rowL * 128 + ((c ^ (rowL & 15)) * 8));
      *(f16x8*)(VTh + (((size_t)(bsel * NHEAD + hh)) * HDIM + dd) * NTOK +
                nbase + c * 8) = v;
    }
    return;
  }

  // heads epilogue (Q scaled, K plain)
  h16* outp = (which == 0) ? Qh : Kh;
  const float scale = (which == 0) ? QSCALE : 1.0f;
#pragma unroll
  for (int j = 0; j < 4; j++) {
    const int gc = n0 + wc * 64 + j * 16 + l15;
    const float bval = bias[gc];
#pragma unroll
    for (int i = 0; i < 4; i++) {
      const int grb = m0 + wr * 64 + i * 16 + lhi * 4;
#pragma unroll
      for (int r = 0; r < 4; r++) {
        const float v = (acc[i][j][r] + bval) * scale;
        const int gr = grb + r;
        const int bidx = gr >> 11, n = gr & (NTOK - 1);
        const int hh = gc >> 6, dd = gc & 63;
        outp[(((size_t)(bidx * NHEAD + hh)) * NTOK + n) * HDIM + dd] = (h16)v;
      }
    }
  }
}

// Out projection: f32 out + bias, 512 blocks, XCD-chunked swizzle.
__global__ __launch_bounds__(256, 3)
void gemm_out(const h16* __restrict__ X, const h16* __restrict__ WT,
              const float* __restrict__ bias, float* __restrict__ outp) {
  __shared__ __attribute__((aligned(16))) h16 smem[3 * 8192];
  const int id = blockIdx.x;                 // 512 = 8 * 64
  const int gid = (id & 7) * 64 + (id >> 3);
  const int m0 = (gid >> 3) * 128;
  const int n0 = (gid & 7) * 128;

  const int tid = threadIdx.x;
  const int lane = tid & 63;
  const int w = tid >> 6;
  const int wr = w >> 1, wc = w & 1;
  const int l15 = lane & 15, lhi = lane >> 4;

  f32x4 acc[4][4] = {};

  const int sr = tid >> 2;
  const int pc = tid & 3;
  const int lc = pc ^ ((sr >> 1) & 3);
  const h16* gA0 = X + (size_t)(m0 + sr) * CDIM + lc * 8;
  const h16* gA1 = gA0 + (size_t)64 * CDIM;
  const h16* gB0 = WT + (size_t)(n0 + sr) * CDIM + lc * 8;
  const h16* gB1 = gB0 + (size_t)64 * CDIM;

#define GSTAGE(bi, kt)                                      \
  do {                                                      \
    h16* A_ = smem + (bi) * 8192;                           \
    h16* B_ = A_ + 4096;                                    \
    gload_lds16(gA0 + (kt) * 32, A_ + tid * 8);             \
    gload_lds16(gA1 + (kt) * 32, A_ + (256 + tid) * 8);     \
    gload_lds16(gB0 + (kt) * 32, B_ + tid * 8);             \
    gload_lds16(gB1 + (kt) * 32, B_ + (256 + tid) * 8);     \
  } while (0)

  const int NT = CDIM / 32;
  GSTAGE(0, 0);
  GSTAGE(1, 1);
  const int rswz = (l15 >> 1) & 3;

  int rb = 0, sb = 2;
  for (int kt = 0; kt < NT; ++kt) {
    if (kt + 1 < NT) asm volatile("s_waitcnt vmcnt(4)" ::: "memory");
    else             asm volatile("s_waitcnt vmcnt(0)" ::: "memory");
    __builtin_amdgcn_s_barrier();
    if (kt + 2 < NT) { GSTAGE(sb, kt + 2); sb = (sb == 2) ? 0 : sb + 1; }
    const h16* A_ = smem + rb * 8192;
    const h16* B_ = A_ + 4096;
    rb = (rb == 2) ? 0 : rb + 1;
    f16x8 a[4], bb[4];
#pragma unroll
    for (int i = 0; i < 4; i++)
      a[i] = *(const f16x8*)(A_ + (wr * 64 + i * 16 + l15) * 32 + (lhi ^ rswz) * 8);
#pragma unroll
    for (int i = 0; i < 4; i++)
      bb[i] = *(const f16x8*)(B_ + (wc * 64 + i * 16 + l15) * 32 + (lhi ^ rswz) * 8);
    __builtin_amdgcn_s_setprio(1);
#pragma unroll
    for (int i = 0; i < 4; i++)
#pragma unroll
      for (int j = 0; j < 4; j++)
        acc[i][j] = __builtin_amdgcn_mfma_f32_16x16x32_f16(a[i], bb[j], acc[i][j], 0, 0, 0);
    __builtin_amdgcn_s_setprio(0);
  }
#undef GSTAGE

#pragma unroll
  for (int j = 0; j < 4; j++) {
    const int gc = n0 + wc * 64 + j * 16 + l15;
    const float bval = bias[gc];
#pragma unroll
    for (int i = 0; i < 4; i++) {
      const int grb = m0 + wr * 64 + i * 16 + lhi * 4;
#pragma unroll
      for (int r = 0; r < 4; r++)
        outp[(size_t)(grb + r) * CDIM + gc] = acc[i][j][r] + bval;
    }
  }
}

// ---------------------------------------------------------------------------
// Flash attention with trinity mask. 8-wave blocks, 128 q-rows, KVBLK=64,
// 2-phase DMA pipeline, swapped QK^T (lane owns q-row), defer-max, deferred
// denominator, V01 prefetch before softmax, in-place masking.
__global__ __launch_bounds__(512, 6)
void attn_kernel(const h16* __restrict__ Qh, const h16* __restrict__ Kh,
                 const h16* __restrict__ VTh, h16* __restrict__ AX) {
  __shared__ __attribute__((aligned(16))) h16 Kb[2][64 * 64];
  __shared__ __attribute__((aligned(16))) h16 Vb[2][64 * 64];
  __shared__ __attribute__((aligned(16))) h16 Pl[8][16 * 64];  // XOR-swizzled

  const int tid = threadIdx.x;
  const int lane = tid & 63;
  const int w = tid >> 6;                      // 0..7
  const int l15 = lane & 15, lhi = lane >> 4;
  const int lhi4 = lhi * 4;

  const int id = blockIdx.x;                   // 1024 = 8 XCD * 128
  const int pos = id >> 3;
  const int bh = (id & 7) * 8 + (pos >> 4);    // XCD-grouped bh
  const int qblk = 15 - (pos & 15);            // txt blocks (12-15) first
  const int b = bh >> 4, h = bh & 15;
  const int q0 = qblk * 128;

  const h16* qbase = Qh + (size_t)bh * NTOK * HDIM;
  const h16* kbase = Kh + (size_t)bh * NTOK * HDIM;
  const h16* vbase = VTh + (size_t)bh * HDIM * NTOK;

  const int qrow = q0 + w * 16 + l15;
  const f16x8 qf0 = *(const f16x8*)(qbase + (size_t)qrow * HDIM + lhi * 8);
  const f16x8 qf1 = *(const f16x8*)(qbase + (size_t)qrow * HDIM + 32 + lhi * 8);
  const int qg = qrow;

  const bool is_img = (q0 < IMGTOK);
  const int kstart = is_img ? (q0 & ~511) : 0;
  const int kend = is_img ? (kstart + 512) : (q0 + 128);
  const int nt = (kend - kstart) >> 6;

  float m = -3.0e38f, lp = 0.f;
  f32x4 o[4] = {};

  // staging: 512 threads cover one 64x64 tile (512 x 16B) per matrix
  const int srow = tid >> 3;
  const int scc = (tid & 7) ^ (srow & 7);
#define ASTAGE(bufi, k0s)                                                     \
  do {                                                                        \
    gload_lds16(kbase + (size_t)((k0s) + srow) * HDIM + scc * 8,              \
                Kb[bufi] + tid * 8);                                          \
    gload_lds16(vbase + (size_t)srow * NTOK + (k0s) + scc * 8,                \
                Vb[bufi] + tid * 8);                                          \
  } while (0)

  h16* pl = &Pl[w][0];
  const int x0 = (lhi ^ (l15 & 7)) * 8;
  const int x1 = ((lhi + 4) ^ (l15 & 7)) * 8;
  const int pswz = l15 & 7;
  const int phalf = (lhi & 1) * 4;
  const int plhi2 = lhi >> 1;
  h16* prb = pl + l15 * 64;

  ASTAGE(0, kstart);
  asm volatile("s_waitcnt vmcnt(0)" ::: "memory");
  __builtin_amdgcn_s_barrier();
  int cur = 0;

  for (int t = 0; t < nt; ++t) {
    const int k0 = kstart + t * 64;
    if (t + 1 < nt) ASTAGE(cur ^ 1, k0 + 64);

    // ---- S^T = K Q^T : 4 blocks of 16 keys ---------------------------
    const h16* Kc = Kb[cur];
    f32x4 s[4];
    __builtin_amdgcn_s_setprio(1);
#pragma unroll
    for (int hk = 0; hk < 4; ++hk) {
      const h16* kr = Kc + (hk * 16 + l15) * 64;
      const f16x8 kfa = *(const f16x8*)(kr + x0);
      const f16x8 kfb = *(const f16x8*)(kr + x1);
      f32x4 acc = {};
      acc = __builtin_amdgcn_mfma_f32_16x16x32_f16(kfa, qf0, acc, 0, 0, 0);
      acc = __builtin_amdgcn_mfma_f32_16x16x32_f16(kfb, qf1, acc, 0, 0, 0);
      s[hk] = acc;
    }
    __builtin_amdgcn_s_setprio(0);

    // ---- V01 prefetch (P-independent; latency hides under softmax) ----
    const h16* Vc = Vb[cur];
    const h16* vr0 = Vc + l15 * 64;
    const h16* vr1 = Vc + (16 + l15) * 64;
    const f16x8 va0 = *(const f16x8*)(vr0 + x0);
    const f16x8 vb0 = *(const f16x8*)(vr0 + x1);
    const f16x8 va1 = *(const f16x8*)(vr1 + x0);
    const f16x8 vb1 = *(const f16x8*)(vr1 + x1);

    // ---- mask in place, lane-local max --------------------------------
    const bool need_mask = (!is_img) && (k0 + 63 >= IMGTOK);
    if (need_mask) {
#pragma unroll
      for (int hk = 0; hk < 4; ++hk)
#pragma unroll
        for (int r = 0; r < 4; ++r) {
          const int kg = k0 + hk * 16 + lhi4 + r;
          if (kg >= IMGTOK && kg > qg) s[hk][r] = -1e30f;
        }
    }
    float lmax = -3.0e38f;
#pragma unroll
    for (int hk = 0; hk < 4; ++hk)
#pragma unroll
      for (int r = 0; r < 4; ++r) lmax = fmaxf(lmax, s[hk][r]);

    if (__any(lmax > m + 8.0f)) {   // rare: row-reduce + rescale
      float vmax = fmaxf(lmax, __shfl_xor(lmax, 16));
      vmax = fmaxf(vmax, __shfl_xor(vmax, 32));
      const float mnew = fmaxf(m, vmax);
      const float corr = exp2f(m - mnew);
      m = mnew;
      lp *= corr;
      const float c0 = __shfl(corr, lhi4 + 0);
      const float c1 = __shfl(corr, lhi4 + 1);
      const float c2 = __shfl(corr, lhi4 + 2);
      const float c3 = __shfl(corr, lhi4 + 3);
#pragma unroll
      for (int dt = 0; dt < 4; dt++) {
        o[dt][0] *= c0; o[dt][1] *= c1; o[dt][2] *= c2; o[dt][3] *= c3;
      }
    }
#pragma unroll
    for (int hk = 0; hk < 4; ++hk) {
      const float e0 = exp2f(s[hk][0] - m);
      const float e1 = exp2f(s[hk][1] - m);
      const float e2 = exp2f(s[hk][2] - m);
      const float e3 = exp2f(s[hk][3] - m);
      lp += (e0 + e1) + (e2 + e3);
      const fp16v2 lo2 = __builtin_amdgcn_cvt_pkrtz(e0, e1);
      const fp16v2 hi2 = __builtin_amdgcn_cvt_pkrtz(e2, e3);
      uint2 qw;
      qw.x = __builtin_bit_cast(unsigned int, lo2);
      qw.y = __builtin_bit_cast(unsigned int, hi2);
      *(uint2*)(prb + ((hk * 2 + plhi2) ^ pswz) * 8 + phalf) = qw;
    }

    // ---- V23 + P reads, then single drain -----------------------------
    const h16* vr2 = Vc + (32 + l15) * 64;
    const h16* vr3 = Vc + (48 + l15) * 64;
    const f16x8 va2 = *(const f16x8*)(vr2 + x0);
    const f16x8 vb2 = *(const f16x8*)(vr2 + x1);
    const f16x8 va3 = *(const f16x8*)(vr3 + x0);
    const f16x8 vb3 = *(const f16x8*)(vr3 + x1);
    const f16x8 pf0 = *(const f16x8*)(pl + l15 * 64 + x0);
    const f16x8 pf1 = *(const f16x8*)(pl + l15 * 64 + x1);
    asm volatile("s_waitcnt lgkmcnt(0)" ::: "memory");
    __builtin_amdgcn_sched_barrier(0);

    // ---- PV -----------------------------------------------------------
    __builtin_amdgcn_s_setprio(1);
    o[0] = __builtin_amdgcn_mfma_f32_16x16x32_f16(pf0, va0, o[0], 0, 0, 0);
    o[0] = __builtin_amdgcn_mfma_f32_16x16x32_f16(pf1, vb0, o[0], 0, 0, 0);
    o[1] = __builtin_amdgcn_mfma_f32_16x16x32_f16(pf0, va1, o[1], 0, 0, 0);
    o[1] = __builtin_amdgcn_mfma_f32_16x16x32_f16(pf1, vb1, o[1], 0, 0, 0);
    o[2] = __builtin_amdgcn_mfma_f32_16x16x32_f16(pf0, va2, o[2], 0, 0, 0);
    o[2] = __builtin_amdgcn_mfma_f32_16x16x32_f16(pf1, vb2, o[2], 0, 0, 0);
    o[3] = __builtin_amdgcn_mfma_f32_16x16x32_f16(pf0, va3, o[3], 0, 0, 0);
    o[3] = __builtin_amdgcn_mfma_f32_16x16x32_f16(pf1, vb3, o[3], 0, 0, 0);
    __builtin_amdgcn_s_setprio(0);

    asm volatile("s_waitcnt vmcnt(0)" ::: "memory");  // next tile DMA landed
    __builtin_amdgcn_s_barrier();                     // all waves off buf[cur]
    cur ^= 1;
  }
#undef ASTAGE

  // epilogue: finish denominator (reduce over lhi groups), write out
  float l = lp;
  l += __shfl_xor(l, 16);
  l += __shfl_xor(l, 32);
  const int qg0 = q0 + w * 16 + lhi4;
#pragma unroll
  for (int r = 0; r < 4; r++) {
    const float lr = __shfl(l, lhi4 + r);
    const float inv = 1.0f / lr;
    const size_t row = (size_t)(b * NTOK + qg0 + r);
#pragma unroll
    for (int dt = 0; dt < 4; dt++) {
      const int col = h * 64 + dt * 16 + l15;
      AX[row * CDIM + col] = (h16)(o[dt][r] * inv);
    }
  }
}

// ---------------------------------------------------------------------------
extern "C" void kernel_launch(void* const* d_in, const int* in_sizes, int n_in,
                              void* d_out, int out_size, void* d_ws, size_t ws_size,
                              hipStream_t stream) {
  (void)in_sizes; (void)n_in; (void)out_size; (void)ws_size;
  const float* q  = (const float*)d_in[0];
  const float* kv = (const float*)d_in[1];
  const float* Wq = (const float*)d_in[2];
  const float* bq = (const float*)d_in[3];
  const float* Wk = (const float*)d_in[4];
  const float* bk = (const float*)d_in[5];
  const float* Wv = (const float*)d_in[6];
  const float* bv = (const float*)d_in[7];
  const float* Wo = (const float*)d_in[8];
  const float* bo = (const float*)d_in[9];
  float* out = (float*)d_out;

  char* ws = (char*)d_ws;
  const size_t SZ_MK = (size_t)MROWS * CDIM * sizeof(h16);  // 16 MB
  const size_t SZ_W  = (size_t)CDIM * CDIM * sizeof(h16);   // 2 MB
  h16* qb  = (h16*)(ws);
  h16* kvb = (h16*)(ws + SZ_MK);
  h16* wqt = (h16*)(ws + 2 * SZ_MK);
  h16* wkt = (h16*)(ws + 2 * SZ_MK + SZ_W);
  h16* wvt = (h16*)(ws + 2 * SZ_MK + 2 * SZ_W);
  h16* wot = (h16*)(ws + 2 * SZ_MK + 3 * SZ_W);
  h16* Qh  = (h16*)(ws + 2 * SZ_MK + 4 * SZ_W);
  h16* Kh  = (h16*)(ws + 3 * SZ_MK + 4 * SZ_W);
  h16* VTh = (h16*)(ws + 4 * SZ_MK + 4 * SZ_W);
  h16* ax  = (h16*)(ws);  // overlays qb (qb dead after Q projection)

  cvt_f16<<<4096, 256, 0, stream>>>(q, qb);
  cvt_f16<<<4096, 256, 0, stream>>>(kv, kvb);
  wtrans<<<dim3(32, 32, 4), dim3(32, 8), 0, stream>>>(Wq, Wk, Wv, Wo,
                                                      wqt, wkt, wvt, wot);
  gemm_qkv<<<1536, 256, 0, stream>>>(qb, kvb, wqt, wkt, wvt, bq, bk, bv,
                                     Qh, Kh, VTh);
  attn_kernel<<<1024, 512, 0, stream>>>(Qh, Kh, VTh, ax);
  gemm_out<<<512, 256, 0, stream>>>(ax, wot, bo, out);
}

// Round 7
// 320.752 us; speedup vs baseline: 1.1626x; 1.1626x over previous
//
#include <hip/hip_runtime.h>

// ---------------------------------------------------------------------------
// CrossAttention (trinity mask) on MI355X.
// B=4, N=2048 (IMG=1536 in 3 chunks of 512, TXT=512), C=1024, H=16, d=64.
// R7: attn reverted to R5 geometry (4 waves, no launch-bounds VGPR cap —
//     R6's (512,6) caused spills: WRITE_SIZE 16->146MB) + V01 prefetch;
//     fused QKV GEMM upgraded to 256x256 tile / 8 waves / 3-buffer counted
//     vmcnt pipeline (1 block/CU, 96KB LDS); out-proj stays 128^2.
// fp16 fragments + f32 accumulation (bf16 would blow absmax through the
// 4-matmul chain; fp16 is same MFMA rate on gfx950).
// ---------------------------------------------------------------------------

typedef _Float16 h16;
typedef _Float16 f16x8 __attribute__((ext_vector_type(8)));
typedef __fp16 fp16v2 __attribute__((ext_vector_type(2)));
typedef float f32x4 __attribute__((ext_vector_type(4)));

#define BATCH 4
#define NTOK  2048
#define CDIM  1024
#define NHEAD 16
#define HDIM  64
#define IMGTOK 1536
#define MROWS (BATCH * NTOK)   // 8192
#define QSCALE 0.18033688011112042f   /* 0.125 * log2(e) */

__device__ __forceinline__ void gload_lds16(const void* g, void* l) {
  __builtin_amdgcn_global_load_lds(
      (const __attribute__((address_space(1))) unsigned int*)g,
      (__attribute__((address_space(3))) unsigned int*)l, 16, 0, 0);
}

// ---------------------------------------------------------------------------
// f32 -> fp16 elementwise convert, 8 elems/thread
__global__ __launch_bounds__(256)
void cvt_f16(const float* __restrict__ s, h16* __restrict__ d) {
  size_t i = ((size_t)blockIdx.x * 256 + threadIdx.x) * 8;
  float4 a = *(const float4*)(s + i);
  float4 b = *(const float4*)(s + i + 4);
  f16x8 o;
  o[0] = (h16)a.x; o[1] = (h16)a.y; o[2] = (h16)a.z; o[3] = (h16)a.w;
  o[4] = (h16)b.x; o[5] = (h16)b.y; o[6] = (h16)b.z; o[7] = (h16)b.w;
  *(f16x8*)(d + i) = o;
}

// ---------------------------------------------------------------------------
// W [K=1024][N=1024] f32  ->  WT [N][K] fp16   (4 weights via blockIdx.z)
__global__ __launch_bounds__(256)
void wtrans(const float* __restrict__ W0, const float* __restrict__ W1,
            const float* __restrict__ W2, const float* __restrict__ W3,
            h16* __restrict__ T0, h16* __restrict__ T1,
            h16* __restrict__ T2, h16* __restrict__ T3) {
  const float* W; h16* T;
  switch (blockIdx.z) {
    case 0: W = W0; T = T0; break;
    case 1: W = W1; T = T1; break;
    case 2: W = W2; T = T2; break;
    default: W = W3; T = T3; break;
  }
  __shared__ float t[32][33];
  const int n0 = blockIdx.x * 32, k0 = blockIdx.y * 32;
  const int tx = threadIdx.x, ty = threadIdx.y;  // (32,8)
#pragma unroll
  for (int i = 0; i < 4; i++)
    t[ty + 8 * i][tx] = W[(size_t)(k0 + ty + 8 * i) * CDIM + n0 + tx];
  __syncthreads();
#pragma unroll
  for (int i = 0; i < 4; i++)
    T[(size_t)(n0 + ty + 8 * i) * CDIM + k0 + tx] = (h16)t[tx][ty + 8 * i];
}

// ---------------------------------------------------------------------------
// Fused QKV projection, 256x256 tile, BK=32, 8 waves (2M x 4N), 3-buffer
// (96KB) counted-vmcnt(4) pipeline, 1 block/CU. 384 blocks = 8 XCD x 48.
// which=0: Qh heads * QSCALE; which=1: Kh heads; which=2: VTh headsT.
__global__ __launch_bounds__(512, 1)
void gemm_qkv(const h16* __restrict__ qb, const h16* __restrict__ kvb,
              const h16* __restrict__ wqt, const h16* __restrict__ wkt,
              const h16* __restrict__ wvt,
              const float* __restrict__ bq, const float* __restrict__ bk,
              const float* __restrict__ bv,
              h16* __restrict__ Qh, h16* __restrict__ Kh,
              h16* __restrict__ VTh) {
  __shared__ __attribute__((aligned(16))) h16 smem[3 * 16384];  // 96 KiB
  const int id = blockIdx.x;                 // 384 = 8 XCD * 48
  const int gid = (id & 7) * 48 + (id >> 3);
  const int which = gid >> 7;                // 0..2
  const int lid = gid & 127;
  const int m0 = (lid >> 2) * 256;
  const int n0 = (lid & 3) * 256;
  const h16* X  = (which == 0) ? qb : kvb;
  const h16* WT = (which == 0) ? wqt : ((which == 1) ? wkt : wvt);
  const float* bias = (which == 0) ? bq : ((which == 1) ? bk : bv);

  const int tid = threadIdx.x;
  const int lane = tid & 63;
  const int w = tid >> 6;                    // 0..7
  const int wr = w >> 2, wc = w & 3;         // 2M x 4N
  const int l15 = lane & 15, lhi = lane >> 4;
  const int lhi4 = lhi * 4;

  f32x4 acc[8][4] = {};

  const int sr = tid >> 2;                   // staging row 0..127 (and +128)
  const int pc = tid & 3;
  const int lc = pc ^ ((sr >> 1) & 3);       // chunk-XOR swizzle
  const h16* gA0 = X + (size_t)(m0 + sr) * CDIM + lc * 8;
  const h16* gA1 = gA0 + (size_t)128 * CDIM;
  const h16* gB0 = WT + (size_t)(n0 + sr) * CDIM + lc * 8;
  const h16* gB1 = gB0 + (size_t)128 * CDIM;

#define GSTAGE(bi, kt)                                      \
  do {                                                      \
    h16* A_ = smem + (bi) * 16384;                          \
    h16* B_ = A_ + 8192;                                    \
    gload_lds16(gA0 + (kt) * 32, A_ + tid * 8);             \
    gload_lds16(gA1 + (kt) * 32, A_ + (512 + tid) * 8);     \
    gload_lds16(gB0 + (kt) * 32, B_ + tid * 8);             \
    gload_lds16(gB1 + (kt) * 32, B_ + (512 + tid) * 8);     \
  } while (0)

  const int NT = CDIM / 32;                  // 32
  GSTAGE(0, 0);
  GSTAGE(1, 1);
  const int rswz = (l15 >> 1) & 3;

  int rb = 0, sb = 2;
  for (int kt = 0; kt < NT; ++kt) {
    if (kt + 1 < NT) asm volatile("s_waitcnt vmcnt(4)" ::: "memory");
    else             asm volatile("s_waitcnt vmcnt(0)" ::: "memory");
    __builtin_amdgcn_s_barrier();
    if (kt + 2 < NT) { GSTAGE(sb, kt + 2); sb = (sb == 2) ? 0 : sb + 1; }
    const h16* A_ = smem + rb * 16384;
    const h16* B_ = A_ + 8192;
    rb = (rb == 2) ? 0 : rb + 1;
    f16x8 a[8], bb[4];
#pragma unroll
    for (int i = 0; i < 8; i++)
      a[i] = *(const f16x8*)(A_ + (wr * 128 + i * 16 + l15) * 32 + (lhi ^ rswz) * 8);
#pragma unroll
    for (int j = 0; j < 4; j++)
      bb[j] = *(const f16x8*)(B_ + (wc * 64 + j * 16 + l15) * 32 + (lhi ^ rswz) * 8);
    __builtin_amdgcn_s_setprio(1);
#pragma unroll
    for (int i = 0; i < 8; i++)
#pragma unroll
      for (int j = 0; j < 4; j++)
        acc[i][j] = __builtin_amdgcn_mfma_f32_16x16x32_f16(a[i], bb[j], acc[i][j], 0, 0, 0);
    __builtin_amdgcn_s_setprio(0);
  }
#undef GSTAGE

  if (which == 2) {
    // Transpose epilogue in two 64KB halves -> VTh [B,H,64,N]
    const int bsel = m0 >> 11;
    const int nbase = m0 & (NTOK - 1);
    h16* T = smem;  // [128][256] h16
    for (int hh2 = 0; hh2 < 2; ++hh2) {
      __builtin_amdgcn_s_barrier();
      if ((wc >> 1) == hh2) {
#pragma unroll
        for (int j = 0; j < 4; j++) {
          const int gcL = wc * 64 + j * 16 + l15;   // absolute col 0..255
          const int row = gcL & 127;
          const float bval = bias[n0 + gcL];
#pragma unroll
          for (int i = 0; i < 8; i++) {
#pragma unroll
            for (int r = 0; r < 4; r++) {
              const int grL = wr * 128 + i * 16 + lhi4 + r;  // 0..255
              const int ch = (grL >> 3) ^ (row & 31);
              T[row * 256 + ch * 8 + (grL & 7)] = (h16)(acc[i][j][r] + bval);
            }
          }
        }
      }
      __builtin_amdgcn_s_barrier();
#pragma unroll
      for (int pass = 0; pass < 8; ++pass) {
        const int rowL = pass * 16 + (tid >> 5);    // 0..127
        const int c = tid & 31;                     // chunk of 8 tokens
        const int gc = n0 + hh2 * 128 + rowL;
        const int hh = gc >> 6, dd = gc & 63;
        f16x8 v = *(const f16x8*)(T + rowL * 256 + ((c ^ (rowL & 31)) * 8));
        *(f16x8*)(VTh + (((size_t)(bsel * NHEAD + hh)) * HDIM + dd) * NTOK +
                  nbase + c * 8) = v;
      }
    }
    return;
  }

  // heads epilogue (Q scaled, K plain)
  h16* outp = (which == 0) ? Qh : Kh;
  const float scale = (which == 0) ? QSCALE : 1.0f;
#pragma unroll
  for (int j = 0; j < 4; j++) {
    const int gc = n0 + wc * 64 + j * 16 + l15;
    const float bval = bias[gc];
    const int hh = gc >> 6, dd = gc & 63;
#pragma unroll
    for (int i = 0; i < 8; i++) {
      const int grb = m0 + wr * 128 + i * 16 + lhi4;
#pragma unroll
      for (int r = 0; r < 4; r++) {
        const float v = (acc[i][j][r] + bval) * scale;
        const int gr = grb + r;
        const int bidx = gr >> 11, n = gr & (NTOK - 1);
        outp[(((size_t)(bidx * NHEAD + hh)) * NTOK + n) * HDIM + dd] = (h16)v;
      }
    }
  }
}

// ---------------------------------------------------------------------------
// Out projection: 128x128 tile, 4 waves, 3-buffer counted-vmcnt pipeline,
// f32 out + bias. 512 blocks, XCD-chunked swizzle.
__global__ __launch_bounds__(256, 3)
void gemm_out(const h16* __restrict__ X, const h16* __restrict__ WT,
              const float* __restrict__ bias, float* __restrict__ outp) {
  __shared__ __attribute__((aligned(16))) h16 smem[3 * 8192];
  const int id = blockIdx.x;                 // 512 = 8 * 64
  const int gid = (id & 7) * 64 + (id >> 3);
  const int m0 = (gid >> 3) * 128;
  const int n0 = (gid & 7) * 128;

  const int tid = threadIdx.x;
  const int lane = tid & 63;
  const int w = tid >> 6;
  const int wr = w >> 1, wc = w & 1;
  const int l15 = lane & 15, lhi = lane >> 4;

  f32x4 acc[4][4] = {};

  const int sr = tid >> 2;
  const int pc = tid & 3;
  const int lc = pc ^ ((sr >> 1) & 3);
  const h16* gA0 = X + (size_t)(m0 + sr) * CDIM + lc * 8;
  const h16* gA1 = gA0 + (size_t)64 * CDIM;
  const h16* gB0 = WT + (size_t)(n0 + sr) * CDIM + lc * 8;
  const h16* gB1 = gB0 + (size_t)64 * CDIM;

#define GSTAGE(bi, kt)                                      \
  do {                                                      \
    h16* A_ = smem + (bi) * 8192;                           \
    h16* B_ = A_ + 4096;                                    \
    gload_lds16(gA0 + (kt) * 32, A_ + tid * 8);             \
    gload_lds16(gA1 + (kt) * 32, A_ + (256 + tid) * 8);     \
    gload_lds16(gB0 + (kt) * 32, B_ + tid * 8);             \
    gload_lds16(gB1 + (kt) * 32, B_ + (256 + tid) * 8);     \
  } while (0)

  const int NT = CDIM / 32;
  GSTAGE(0, 0);
  GSTAGE(1, 1);
  const int rswz = (l15 >> 1) & 3;

  int rb = 0, sb = 2;
  for (int kt = 0; kt < NT; ++kt) {
    if (kt + 1 < NT) asm volatile("s_waitcnt vmcnt(4)" ::: "memory");
    else             asm volatile("s_waitcnt vmcnt(0)" ::: "memory");
    __builtin_amdgcn_s_barrier();
    if (kt + 2 < NT) { GSTAGE(sb, kt + 2); sb = (sb == 2) ? 0 : sb + 1; }
    const h16* A_ = smem + rb * 8192;
    const h16* B_ = A_ + 4096;
    rb = (rb == 2) ? 0 : rb + 1;
    f16x8 a[4], bb[4];
#pragma unroll
    for (int i = 0; i < 4; i++)
      a[i] = *(const f16x8*)(A_ + (wr * 64 + i * 16 + l15) * 32 + (lhi ^ rswz) * 8);
#pragma unroll
    for (int i = 0; i < 4; i++)
      bb[i] = *(const f16x8*)(B_ + (wc * 64 + i * 16 + l15) * 32 + (lhi ^ rswz) * 8);
    __builtin_amdgcn_s_setprio(1);
#pragma unroll
    for (int i = 0; i < 4; i++)
#pragma unroll
      for (int j = 0; j < 4; j++)
        acc[i][j] = __builtin_amdgcn_mfma_f32_16x16x32_f16(a[i], bb[j], acc[i][j], 0, 0, 0);
    __builtin_amdgcn_s_setprio(0);
  }
#undef GSTAGE

#pragma unroll
  for (int j = 0; j < 4; j++) {
    const int gc = n0 + wc * 64 + j * 16 + l15;
    const float bval = bias[gc];
#pragma unroll
    for (int i = 0; i < 4; i++) {
      const int grb = m0 + wr * 64 + i * 16 + (lhi << 2);
#pragma unroll
      for (int r = 0; r < 4; r++)
        outp[(size_t)(grb + r) * CDIM + gc] = acc[i][j][r] + bval;
    }
  }
}

// ---------------------------------------------------------------------------
// Flash attention with trinity mask. R5 geometry: 4 waves / 2048 blocks /
// 40KB LDS (4 blocks/CU), 2-phase DMA pipeline, KVBLK=64, swapped QK^T,
// defer-max + deferred denominator, V01 prefetch before softmax.
__global__ __launch_bounds__(256)
void attn_kernel(const h16* __restrict__ Qh, const h16* __restrict__ Kh,
                 const h16* __restrict__ VTh, h16* __restrict__ AX) {
  __shared__ __attribute__((aligned(16))) h16 Kb[2][64 * 64];
  __shared__ __attribute__((aligned(16))) h16 Vb[2][64 * 64];
  __shared__ __attribute__((aligned(16))) h16 Pl[4][16 * 64];  // XOR-swizzled

  const int tid = threadIdx.x;
  const int lane = tid & 63;
  const int w = tid >> 6;
  const int l15 = lane & 15, lhi = lane >> 4;
  const int lhi4 = lhi * 4;

  const int id = blockIdx.x;
  const int pos = id >> 3;
  const int bh = (id & 7) * 8 + (pos >> 5);   // XCD-grouped bh
  const int qblk = 31 - (pos & 31);           // text-first (long blocks early)
  const int b = bh >> 4, h = bh & 15;
  const int q0 = qblk * 64;

  const h16* qbase = Qh + (size_t)bh * NTOK * HDIM;
  const h16* kbase = Kh + (size_t)bh * NTOK * HDIM;
  const h16* vbase = VTh + (size_t)bh * HDIM * NTOK;

  // Q fragments (B operand after swap): col=lane&15 -> q-row, k=(lane>>4)*8
  const int qrow = q0 + w * 16 + l15;
  const f16x8 qf0 = *(const f16x8*)(qbase + (size_t)qrow * HDIM + lhi * 8);
  const f16x8 qf1 = *(const f16x8*)(qbase + (size_t)qrow * HDIM + 32 + lhi * 8);
  const int qg = qrow;

  const bool is_img = (q0 < IMGTOK);
  int kstart, kend;
  if (is_img) { kstart = q0 & ~511; kend = kstart + 512; }
  else        { kstart = 0;         kend = q0 + 64; }
  const int nt = (kend - kstart) >> 6;

  float m = -3.0e38f, lp = 0.f;
  f32x4 o[4] = {};

  // staging: physical chunk p -> row p>>3; logical col-chunk = (p&7)^(row&7)
  const int srow = tid >> 3;
  const int scc = (tid & 7) ^ (srow & 7);
#define ASTAGE(bufi, k0s)                                                     \
  do {                                                                        \
    gload_lds16(kbase + (size_t)((k0s) + srow) * HDIM + scc * 8,              \
                Kb[bufi] + tid * 8);                                          \
    gload_lds16(kbase + (size_t)((k0s) + 32 + srow) * HDIM + scc * 8,         \
                Kb[bufi] + (256 + tid) * 8);                                  \
    gload_lds16(vbase + (size_t)srow * NTOK + (k0s) + scc * 8,                \
                Vb[bufi] + tid * 8);                                          \
    gload_lds16(vbase + (size_t)(32 + srow) * NTOK + (k0s) + scc * 8,         \
                Vb[bufi] + (256 + tid) * 8);                                  \
  } while (0)

  h16* pl = &Pl[w][0];
  const int x0 = (lhi ^ (l15 & 7)) * 8;
  const int x1 = ((lhi + 4) ^ (l15 & 7)) * 8;
  const int pswz = l15 & 7;
  const int phalf = (lhi & 1) * 4;
  const int plhi2 = lhi >> 1;
  h16* prb = pl + l15 * 64;

  ASTAGE(0, kstart);
  asm volatile("s_waitcnt vmcnt(0)" ::: "memory");
  __builtin_amdgcn_s_barrier();
  int cur = 0;

  for (int t = 0; t < nt; ++t) {
    const int k0 = kstart + t * 64;
    if (t + 1 < nt) ASTAGE(cur ^ 1, k0 + 64);

    // ---- S^T = K Q^T : 4 blocks of 16 keys ---------------------------
    const h16* Kc = Kb[cur];
    f32x4 s[4];
    __builtin_amdgcn_s_setprio(1);
#pragma unroll
    for (int hk = 0; hk < 4; ++hk) {
      const h16* kr = Kc + (hk * 16 + l15) * 64;
      const f16x8 kfa = *(const f16x8*)(kr + x0);
      const f16x8 kfb = *(const f16x8*)(kr + x1);
      f32x4 acc = {};
      acc = __builtin_amdgcn_mfma_f32_16x16x32_f16(kfa, qf0, acc, 0, 0, 0);
      acc = __builtin_amdgcn_mfma_f32_16x16x32_f16(kfb, qf1, acc, 0, 0, 0);
      s[hk] = acc;
    }
    __builtin_amdgcn_s_setprio(0);

    // ---- V01 prefetch (P-independent; hides under softmax) ------------
    const h16* Vc = Vb[cur];
    const h16* vr0 = Vc + l15 * 64;
    const h16* vr1 = Vc + (16 + l15) * 64;
    const f16x8 va0 = *(const f16x8*)(vr0 + x0);
    const f16x8 vb0 = *(const f16x8*)(vr0 + x1);
    const f16x8 va1 = *(const f16x8*)(vr1 + x0);
    const f16x8 vb1 = *(const f16x8*)(vr1 + x1);

    // ---- lane-local softmax (defer-max, deferred sum, in-place mask) ---
    const bool need_mask = (!is_img) && (k0 + 63 >= IMGTOK);
    if (need_mask) {
#pragma unroll
      for (int hk = 0; hk < 4; ++hk)
#pragma unroll
        for (int r = 0; r < 4; ++r) {
          const int kg = k0 + hk * 16 + lhi4 + r;
          if (kg >= IMGTOK && kg > qg) s[hk][r] = -1e30f;
        }
    }
    float lmax = -3.0e38f;
#pragma unroll
    for (int hk = 0; hk < 4; ++hk)
#pragma unroll
      for (int r = 0; r < 4; ++r) lmax = fmaxf(lmax, s[hk][r]);

    if (__any(lmax > m + 8.0f)) {   // rare: row-reduce + rescale
      float vmax = fmaxf(lmax, __shfl_xor(lmax, 16));
      vmax = fmaxf(vmax, __shfl_xor(vmax, 32));
      const float mnew = fmaxf(m, vmax);
      const float corr = exp2f(m - mnew);
      m = mnew;
      lp *= corr;
      const float c0 = __shfl(corr, lhi4 + 0);
      const float c1 = __shfl(corr, lhi4 + 1);
      const float c2 = __shfl(corr, lhi4 + 2);
      const float c3 = __shfl(corr, lhi4 + 3);
#pragma unroll
      for (int dt = 0; dt < 4; dt++) {
        o[dt][0] *= c0; o[dt][1] *= c1; o[dt][2] *= c2; o[dt][3] *= c3;
      }
    }
#pragma unroll
    for (int hk = 0; hk < 4; ++hk) {
      const float e0 = exp2f(s[hk][0] - m);
      const float e1 = exp2f(s[hk][1] - m);
      const float e2 = exp2f(s[hk][2] - m);
      const float e3 = exp2f(s[hk][3] - m);
      lp += (e0 + e1) + (e2 + e3);
      const fp16v2 lo2 = __builtin_amdgcn_cvt_pkrtz(e0, e1);
      const fp16v2 hi2 = __builtin_amdgcn_cvt_pkrtz(e2, e3);
      uint2 qw;
      qw.x = __builtin_bit_cast(unsigned int, lo2);
      qw.y = __builtin_bit_cast(unsigned int, hi2);
      *(uint2*)(prb + ((hk * 2 + plhi2) ^ pswz) * 8 + phalf) = qw;
    }

    // ---- V23 + P reads, then single drain -----------------------------
    const h16* vr2 = Vc + (32 + l15) * 64;
    const h16* vr3 = Vc + (48 + l15) * 64;
    const f16x8 va2 = *(const f16x8*)(vr2 + x0);
    const f16x8 vb2 = *(const f16x8*)(vr2 + x1);
    const f16x8 va3 = *(const f16x8*)(vr3 + x0);
    const f16x8 vb3 = *(const f16x8*)(vr3 + x1);
    const f16x8 pf0 = *(const f16x8*)(pl + l15 * 64 + x0);
    const f16x8 pf1 = *(const f16x8*)(pl + l15 * 64 + x1);
    asm volatile("s_waitcnt lgkmcnt(0)" ::: "memory");
    __builtin_amdgcn_sched_barrier(0);

    // ---- PV -----------------------------------------------------------
    __builtin_amdgcn_s_setprio(1);
    o[0] = __builtin_amdgcn_mfma_f32_16x16x32_f16(pf0, va0, o[0], 0, 0, 0);
    o[0] = __builtin_amdgcn_mfma_f32_16x16x32_f16(pf1, vb0, o[0], 0, 0, 0);
    o[1] = __builtin_amdgcn_mfma_f32_16x16x32_f16(pf0, va1, o[1], 0, 0, 0);
    o[1] = __builtin_amdgcn_mfma_f32_16x16x32_f16(pf1, vb1, o[1], 0, 0, 0);
    o[2] = __builtin_amdgcn_mfma_f32_16x16x32_f16(pf0, va2, o[2], 0, 0, 0);
    o[2] = __builtin_amdgcn_mfma_f32_16x16x32_f16(pf1, vb2, o[2], 0, 0, 0);
    o[3] = __builtin_amdgcn_mfma_f32_16x16x32_f16(pf0, va3, o[3], 0, 0, 0);
    o[3] = __builtin_amdgcn_mfma_f32_16x16x32_f16(pf1, vb3, o[3], 0, 0, 0);
    __builtin_amdgcn_s_setprio(0);

    asm volatile("s_waitcnt vmcnt(0)" ::: "memory");  // next tile DMA landed
    __builtin_amdgcn_s_barrier();                     // all waves off buf[cur]
    cur ^= 1;
  }
#undef ASTAGE

  // epilogue: finish denominator (reduce over lhi groups), write out
  float l = lp;
  l += __shfl_xor(l, 16);
  l += __shfl_xor(l, 32);
  const int qg0 = q0 + w * 16 + lhi4;
#pragma unroll
  for (int r = 0; r < 4; r++) {
    const float lr = __shfl(l, lhi4 + r);
    const float inv = 1.0f / lr;
    const size_t row = (size_t)(b * NTOK + qg0 + r);
#pragma unroll
    for (int dt = 0; dt < 4; dt++) {
      const int col = h * 64 + dt * 16 + l15;
      AX[row * CDIM + col] = (h16)(o[dt][r] * inv);
    }
  }
}

// ---------------------------------------------------------------------------
extern "C" void kernel_launch(void* const* d_in, const int* in_sizes, int n_in,
                              void* d_out, int out_size, void* d_ws, size_t ws_size,
                              hipStream_t stream) {
  (void)in_sizes; (void)n_in; (void)out_size; (void)ws_size;
  const float* q  = (const float*)d_in[0];
  const float* kv = (const float*)d_in[1];
  const float* Wq = (const float*)d_in[2];
  const float* bq = (const float*)d_in[3];
  const float* Wk = (const float*)d_in[4];
  const float* bk = (const float*)d_in[5];
  const float* Wv = (const float*)d_in[6];
  const float* bv = (const float*)d_in[7];
  const float* Wo = (const float*)d_in[8];
  const float* bo = (const float*)d_in[9];
  float* out = (float*)d_out;

  char* ws = (char*)d_ws;
  const size_t SZ_MK = (size_t)MROWS * CDIM * sizeof(h16);  // 16 MB
  const size_t SZ_W  = (size_t)CDIM * CDIM * sizeof(h16);   // 2 MB
  h16* qb  = (h16*)(ws);
  h16* kvb = (h16*)(ws + SZ_MK);
  h16* wqt = (h16*)(ws + 2 * SZ_MK);
  h16* wkt = (h16*)(ws + 2 * SZ_MK + SZ_W);
  h16* wvt = (h16*)(ws + 2 * SZ_MK + 2 * SZ_W);
  h16* wot = (h16*)(ws + 2 * SZ_MK + 3 * SZ_W);
  h16* Qh  = (h16*)(ws + 2 * SZ_MK + 4 * SZ_W);
  h16* Kh  = (h16*)(ws + 3 * SZ_MK + 4 * SZ_W);
  h16* VTh = (h16*)(ws + 4 * SZ_MK + 4 * SZ_W);
  h16* ax  = (h16*)(ws);  // overlays qb (qb dead after Q projection)

  cvt_f16<<<4096, 256, 0, stream>>>(q, qb);
  cvt_f16<<<4096, 256, 0, stream>>>(kv, kvb);
  wtrans<<<dim3(32, 32, 4), dim3(32, 8), 0, stream>>>(Wq, Wk, Wv, Wo,
                                                      wqt, wkt, wvt, wot);
  gemm_qkv<<<384, 512, 0, stream>>>(qb, kvb, wqt, wkt, wvt, bq, bk, bv,
                                    Qh, Kh, VTh);
  attn_kernel<<<2048, 256, 0, stream>>>(Qh, Kh, VTh, ax);
  gemm_out<<<512, 256, 0, stream>>>(ax, wot, bo, out);
}

// Round 8
// 311.843 us; speedup vs baseline: 1.1958x; 1.0286x over previous
//
#include <hip/hip_runtime.h>

// ---------------------------------------------------------------------------
// CrossAttention (trinity mask) on MI355X.
// B=4, N=2048 (IMG=1536 in 3 chunks of 512, TXT=512), C=1024, H=16, d=64.
// R8: GEMM core rebuilt at BK=64 (128B LDS rows -> full-bank 3-bit XOR
//     swizzle, the pattern attn's counters proved conflict-free), 32 MFMA
//     per barrier-pair, double-buffer + counted vmcnt(8). attn gets
//     triple-buffered K/V with counted vmcnt(4) (no per-tile DMA drain).
// fp16 fragments + f32 accumulation (bf16 would blow absmax through the
// 4-matmul chain; fp16 is same MFMA rate on gfx950).
// ---------------------------------------------------------------------------

typedef _Float16 h16;
typedef _Float16 f16x8 __attribute__((ext_vector_type(8)));
typedef __fp16 fp16v2 __attribute__((ext_vector_type(2)));
typedef float f32x4 __attribute__((ext_vector_type(4)));

#define BATCH 4
#define NTOK  2048
#define CDIM  1024
#define NHEAD 16
#define HDIM  64
#define IMGTOK 1536
#define MROWS (BATCH * NTOK)   // 8192
#define QSCALE 0.18033688011112042f   /* 0.125 * log2(e) */

__device__ __forceinline__ void gload_lds16(const void* g, void* l) {
  __builtin_amdgcn_global_load_lds(
      (const __attribute__((address_space(1))) unsigned int*)g,
      (__attribute__((address_space(3))) unsigned int*)l, 16, 0, 0);
}

// ---------------------------------------------------------------------------
// f32 -> fp16 elementwise convert, 8 elems/thread
__global__ __launch_bounds__(256)
void cvt_f16(const float* __restrict__ s, h16* __restrict__ d) {
  size_t i = ((size_t)blockIdx.x * 256 + threadIdx.x) * 8;
  float4 a = *(const float4*)(s + i);
  float4 b = *(const float4*)(s + i + 4);
  f16x8 o;
  o[0] = (h16)a.x; o[1] = (h16)a.y; o[2] = (h16)a.z; o[3] = (h16)a.w;
  o[4] = (h16)b.x; o[5] = (h16)b.y; o[6] = (h16)b.z; o[7] = (h16)b.w;
  *(f16x8*)(d + i) = o;
}

// ---------------------------------------------------------------------------
// W [K=1024][N=1024] f32  ->  WT [N][K] fp16   (4 weights via blockIdx.z)
__global__ __launch_bounds__(256)
void wtrans(const float* __restrict__ W0, const float* __restrict__ W1,
            const float* __restrict__ W2, const float* __restrict__ W3,
            h16* __restrict__ T0, h16* __restrict__ T1,
            h16* __restrict__ T2, h16* __restrict__ T3) {
  const float* W; h16* T;
  switch (blockIdx.z) {
    case 0: W = W0; T = T0; break;
    case 1: W = W1; T = T1; break;
    case 2: W = W2; T = T2; break;
    default: W = W3; T = T3; break;
  }
  __shared__ float t[32][33];
  const int n0 = blockIdx.x * 32, k0 = blockIdx.y * 32;
  const int tx = threadIdx.x, ty = threadIdx.y;  // (32,8)
#pragma unroll
  for (int i = 0; i < 4; i++)
    t[ty + 8 * i][tx] = W[(size_t)(k0 + ty + 8 * i) * CDIM + n0 + tx];
  __syncthreads();
#pragma unroll
  for (int i = 0; i < 4; i++)
    T[(size_t)(n0 + ty + 8 * i) * CDIM + k0 + tx] = (h16)t[tx][ty + 8 * i];
}

// ---------------------------------------------------------------------------
// Shared GEMM core: 128x128 tile, BK=64 (128B LDS rows), 4 waves, 2-buffer
// 64KB LDS, counted vmcnt(8). LDS layout: slot (r, p) holds global chunk
// p ^ (r&7) of row r  ->  frag read at chunk c uses slot c ^ (r&7); with
// rows at 128B this spreads over all 32 banks (attn-verified pattern).
// Per K-step/wave: 16 ds_read_b128 + 32 MFMA, 2 barriers.

#define GEMM_CORE(X_, WT_)                                                    \
  f32x4 acc[4][4] = {};                                                       \
  const int tid = threadIdx.x;                                                \
  const int lane = tid & 63;                                                  \
  const int w = tid >> 6;                                                     \
  const int wr = w >> 1, wc = w & 1;                                          \
  const int l15 = lane & 15, lhi = lane >> 4;                                 \
  const int srow = tid >> 3;            /* 0..31 (staging row base) */        \
  const int scol = (((tid & 7) ^ (srow & 7)) << 3); /* inv-swz col (h16) */   \
  const h16* gA = X_ + (size_t)(m0 + srow) * CDIM + scol;                     \
  const h16* gB = WT_ + (size_t)(n0 + srow) * CDIM + scol;                    \
  const int x0 = ((lhi ^ (l15 & 7)) << 3);                                    \
  const int x1 = (((lhi + 4) ^ (l15 & 7)) << 3);                              \
  const int NT = CDIM / 64; /* 16 */                                          \
  GSTAGE(0, 0);                                                               \
  for (int kt = 0; kt < NT; ++kt) {                                           \
    if (kt + 1 < NT) {                                                        \
      GSTAGE((kt + 1) & 1, kt + 1);                                           \
      asm volatile("s_waitcnt vmcnt(8)" ::: "memory");                        \
    } else {                                                                  \
      asm volatile("s_waitcnt vmcnt(0)" ::: "memory");                        \
    }                                                                         \
    __builtin_amdgcn_s_barrier();                                             \
    const h16* A_ = smem + (kt & 1) * 16384;                                  \
    const h16* B_ = A_ + 8192;                                                \
    f16x8 a0[4], a1[4], b0[4], b1[4];                                         \
    _Pragma("unroll")                                                         \
    for (int i = 0; i < 4; i++) {                                             \
      const h16* ar = A_ + (wr * 64 + i * 16 + l15) * 64;                     \
      a0[i] = *(const f16x8*)(ar + x0);                                       \
      a1[i] = *(const f16x8*)(ar + x1);                                       \
    }                                                                         \
    _Pragma("unroll")                                                         \
    for (int j = 0; j < 4; j++) {                                             \
      const h16* br = B_ + (wc * 64 + j * 16 + l15) * 64;                     \
      b0[j] = *(const f16x8*)(br + x0);                                       \
      b1[j] = *(const f16x8*)(br + x1);                                       \
    }                                                                         \
    __builtin_amdgcn_s_setprio(1);                                            \
    _Pragma("unroll")                                                         \
    for (int i = 0; i < 4; i++)                                               \
      _Pragma("unroll")                                                       \
      for (int j = 0; j < 4; j++) {                                           \
        acc[i][j] = __builtin_amdgcn_mfma_f32_16x16x32_f16(a0[i], b0[j],      \
                                                           acc[i][j], 0, 0, 0);\
        acc[i][j] = __builtin_amdgcn_mfma_f32_16x16x32_f16(a1[i], b1[j],      \
                                                           acc[i][j], 0, 0, 0);\
      }                                                                       \
    __builtin_amdgcn_s_setprio(0);                                            \
    __builtin_amdgcn_s_barrier();                                             \
  }

// stage: 4 rounds x 256 threads cover A (1024 chunks) and B (1024 chunks)
#define GSTAGE(bi, kt)                                                        \
  do {                                                                        \
    h16* A_ = smem + (bi) * 16384;                                            \
    h16* B_ = A_ + 8192;                                                      \
    _Pragma("unroll")                                                         \
    for (int rd = 0; rd < 4; ++rd) {                                          \
      gload_lds16(gA + (size_t)(rd * 32) * CDIM + (kt) * 64,                  \
                  A_ + (rd * 256 + tid) * 8);                                 \
      gload_lds16(gB + (size_t)(rd * 32) * CDIM + (kt) * 64,                  \
                  B_ + (rd * 256 + tid) * 8);                                 \
    }                                                                         \
  } while (0)

// ---------------------------------------------------------------------------
// Fused QKV projection: 1536 blocks = 8 XCD x 192, 128^2 tiles.
// which=0: Qh heads * QSCALE; which=1: Kh heads; which=2: VTh headsT.
__global__ __launch_bounds__(256, 2)
void gemm_qkv(const h16* __restrict__ qb, const h16* __restrict__ kvb,
              const h16* __restrict__ wqt, const h16* __restrict__ wkt,
              const h16* __restrict__ wvt,
              const float* __restrict__ bq, const float* __restrict__ bk,
              const float* __restrict__ bv,
              h16* __restrict__ Qh, h16* __restrict__ Kh,
              h16* __restrict__ VTh) {
  __shared__ __attribute__((aligned(16))) h16 smem[2 * 16384];  // 64 KiB
  const int id = blockIdx.x;
  const int gid = (id & 7) * 192 + (id >> 3);
  const int which = gid >> 9;                // 0..2
  const int lid = gid & 511;
  const int m0 = (lid >> 3) * 128;
  const int n0 = (lid & 7) * 128;
  const h16* X  = (which == 0) ? qb : kvb;
  const h16* WT = (which == 0) ? wqt : ((which == 1) ? wkt : wvt);
  const float* bias = (which == 0) ? bq : ((which == 1) ? bk : bv);

  GEMM_CORE(X, WT)

  const int lhi4 = lhi * 4;
  if (which == 2) {
    // transpose epilogue -> VTh [B,H,64,N], coalesced 256B rows
    __builtin_amdgcn_s_barrier();
    h16* T = smem;  // [128][128], chunk = (grL>>3) ^ (gcL&15)
#pragma unroll
    for (int j = 0; j < 4; j++) {
      const int gcL = wc * 64 + j * 16 + l15;
      const float bval = bias[n0 + gcL];
#pragma unroll
      for (int i = 0; i < 4; i++) {
#pragma unroll
        for (int r = 0; r < 4; r++) {
          const int grL = wr * 64 + i * 16 + lhi4 + r;
          const int ch = (grL >> 3) ^ (gcL & 15);
          T[gcL * 128 + ch * 8 + (grL & 7)] = (h16)(acc[i][j][r] + bval);
        }
      }
    }
    __builtin_amdgcn_s_barrier();
    const int bsel = m0 >> 11;
    const int nbase = m0 & (NTOK - 1);
#pragma unroll
    for (int pass = 0; pass < 8; ++pass) {
      const int rowL = pass * 16 + (tid >> 4);
      const int c = tid & 15;
      const int gc = n0 + rowL;
      const int hh = gc >> 6, dd = gc & 63;
      f16x8 v = *(const f16x8*)(T + rowL * 128 + ((c ^ (rowL & 15)) * 8));
      *(f16x8*)(VTh + (((size_t)(bsel * NHEAD + hh)) * HDIM + dd) * NTOK +
                nbase + c * 8) = v;
    }
    return;
  }

  // heads epilogue (Q scaled, K plain)
  h16* outp = (which == 0) ? Qh : Kh;
  const float scale = (which == 0) ? QSCALE : 1.0f;
#pragma unroll
  for (int j = 0; j < 4; j++) {
    const int gc = n0 + wc * 64 + j * 16 + l15;
    const float bval = bias[gc];
    const int hh = gc >> 6, dd = gc & 63;
#pragma unroll
    for (int i = 0; i < 4; i++) {
      const int grb = m0 + wr * 64 + i * 16 + lhi4;
#pragma unroll
      for (int r = 0; r < 4; r++) {
        const float v = (acc[i][j][r] + bval) * scale;
        const int gr = grb + r;
        const int bidx = gr >> 11, n = gr & (NTOK - 1);
        outp[(((size_t)(bidx * NHEAD + hh)) * NTOK + n) * HDIM + dd] = (h16)v;
      }
    }
  }
}

// ---------------------------------------------------------------------------
// Out projection: f32 out + bias. 512 blocks = 8 XCD x 64, 128^2 tiles.
__global__ __launch_bounds__(256, 2)
void gemm_out(const h16* __restrict__ X, const h16* __restrict__ WT,
              const float* __restrict__ bias, float* __restrict__ outp) {
  __shared__ __attribute__((aligned(16))) h16 smem[2 * 16384];  // 64 KiB
  const int id = blockIdx.x;
  const int gid = (id & 7) * 64 + (id >> 3);
  const int m0 = (gid >> 3) * 128;
  const int n0 = (gid & 7) * 128;

  GEMM_CORE(X, WT)

#pragma unroll
  for (int j = 0; j < 4; j++) {
    const int gc = n0 + wc * 64 + j * 16 + l15;
    const float bval = bias[gc];
#pragma unroll
    for (int i = 0; i < 4; i++) {
      const int grb = m0 + wr * 64 + i * 16 + lhi * 4;
#pragma unroll
      for (int r = 0; r < 4; r++)
        outp[(size_t)(grb + r) * CDIM + gc] = acc[i][j][r] + bval;
    }
  }
}

// ---------------------------------------------------------------------------
// Flash attention with trinity mask. 4 waves / 2048 blocks, KVBLK=64,
// TRIPLE-buffered K/V (56KB LDS, 2 blocks/CU) with counted vmcnt(4):
// stage t+2 after the single per-tile barrier; no per-tile DMA drain.
// Swapped QK^T (lane owns q-row), defer-max + deferred denominator,
// V prefetch before softmax; Q pre-scaled by 0.125*log2(e).
__global__ __launch_bounds__(256)
void attn_kernel(const h16* __restrict__ Qh, const h16* __restrict__ Kh,
                 const h16* __restrict__ VTh, h16* __restrict__ AX) {
  __shared__ __attribute__((aligned(16))) h16 Kb[3][64 * 64];
  __shared__ __attribute__((aligned(16))) h16 Vb[3][64 * 64];
  __shared__ __attribute__((aligned(16))) h16 Pl[4][16 * 64];  // XOR-swizzled

  const int tid = threadIdx.x;
  const int lane = tid & 63;
  const int w = tid >> 6;
  const int l15 = lane & 15, lhi = lane >> 4;
  const int lhi4 = lhi * 4;

  const int id = blockIdx.x;
  const int pos = id >> 3;
  const int bh = (id & 7) * 8 + (pos >> 5);   // XCD-grouped bh
  const int qblk = 31 - (pos & 31);           // text-first (long blocks early)
  const int b = bh >> 4, h = bh & 15;
  const int q0 = qblk * 64;

  const h16* qbase = Qh + (size_t)bh * NTOK * HDIM;
  const h16* kbase = Kh + (size_t)bh * NTOK * HDIM;
  const h16* vbase = VTh + (size_t)bh * HDIM * NTOK;

  // Q fragments (B operand after swap): col=lane&15 -> q-row, k=(lane>>4)*8
  const int qrow = q0 + w * 16 + l15;
  const f16x8 qf0 = *(const f16x8*)(qbase + (size_t)qrow * HDIM + lhi * 8);
  const f16x8 qf1 = *(const f16x8*)(qbase + (size_t)qrow * HDIM + 32 + lhi * 8);
  const int qg = qrow;

  const bool is_img = (q0 < IMGTOK);
  int kstart, kend;
  if (is_img) { kstart = q0 & ~511; kend = kstart + 512; }
  else        { kstart = 0;         kend = q0 + 64; }
  const int nt = (kend - kstart) >> 6;

  float m = -3.0e38f, lp = 0.f;
  f32x4 o[4] = {};

  // staging: physical chunk p -> row p>>3; logical col-chunk = (p&7)^(row&7)
  const int srow = tid >> 3;
  const int scc = (tid & 7) ^ (srow & 7);
#define ASTAGE(bufi, k0s)                                                     \
  do {                                                                        \
    gload_lds16(kbase + (size_t)((k0s) + srow) * HDIM + scc * 8,              \
                Kb[bufi] + tid * 8);                                          \
    gload_lds16(kbase + (size_t)((k0s) + 32 + srow) * HDIM + scc * 8,         \
                Kb[bufi] + (256 + tid) * 8);                                  \
    gload_lds16(vbase + (size_t)srow * NTOK + (k0s) + scc * 8,                \
                Vb[bufi] + tid * 8);                                          \
    gload_lds16(vbase + (size_t)(32 + srow) * NTOK + (k0s) + scc * 8,         \
                Vb[bufi] + (256 + tid) * 8);                                  \
  } while (0)

  h16* pl = &Pl[w][0];
  const int x0 = (lhi ^ (l15 & 7)) * 8;
  const int x1 = ((lhi + 4) ^ (l15 & 7)) * 8;
  const int pswz = l15 & 7;
  const int phalf = (lhi & 1) * 4;
  const int plhi2 = lhi >> 1;
  h16* prb = pl + l15 * 64;

  ASTAGE(0, kstart);
  if (nt > 1) ASTAGE(1, kstart + 64);
  int cur = 0, sb = 2;

  for (int t = 0; t < nt; ++t) {
    const int k0 = kstart + t * 64;
    if (t + 1 < nt) asm volatile("s_waitcnt vmcnt(4)" ::: "memory");
    else            asm volatile("s_waitcnt vmcnt(0)" ::: "memory");
    __builtin_amdgcn_s_barrier();
    if (t + 2 < nt) { ASTAGE(sb, k0 + 128); sb = (sb == 2) ? 0 : sb + 1; }

    // ---- S^T = K Q^T : 4 blocks of 16 keys ---------------------------
    const h16* Kc = Kb[cur];
    f32x4 s[4];
    __builtin_amdgcn_s_setprio(1);
#pragma unroll
    for (int hk = 0; hk < 4; ++hk) {
      const h16* kr = Kc + (hk * 16 + l15) * 64;
      const f16x8 kfa = *(const f16x8*)(kr + x0);
      const f16x8 kfb = *(const f16x8*)(kr + x1);
      f32x4 acc = {};
      acc = __builtin_amdgcn_mfma_f32_16x16x32_f16(kfa, qf0, acc, 0, 0, 0);
      acc = __builtin_amdgcn_mfma_f32_16x16x32_f16(kfb, qf1, acc, 0, 0, 0);
      s[hk] = acc;
    }
    __builtin_amdgcn_s_setprio(0);

    // ---- V01 prefetch (P-independent; hides under softmax) ------------
    const h16* Vc = Vb[cur];
    const h16* vr0 = Vc + l15 * 64;
    const h16* vr1 = Vc + (16 + l15) * 64;
    const f16x8 va0 = *(const f16x8*)(vr0 + x0);
    const f16x8 vb0 = *(const f16x8*)(vr0 + x1);
    const f16x8 va1 = *(const f16x8*)(vr1 + x0);
    const f16x8 vb1 = *(const f16x8*)(vr1 + x1);

    // ---- lane-local softmax (defer-max, deferred sum, in-place mask) ---
    const bool need_mask = (!is_img) && (k0 + 63 >= IMGTOK);
    if (need_mask) {
#pragma unroll
      for (int hk = 0; hk < 4; ++hk)
#pragma unroll
        for (int r = 0; r < 4; ++r) {
          const int kg = k0 + hk * 16 + lhi4 + r;
          if (kg >= IMGTOK && kg > qg) s[hk][r] = -1e30f;
        }
    }
    float lmax = -3.0e38f;
#pragma unroll
    for (int hk = 0; hk < 4; ++hk)
#pragma unroll
      for (int r = 0; r < 4; ++r) lmax = fmaxf(lmax, s[hk][r]);

    if (__any(lmax > m + 8.0f)) {   // rare: row-reduce + rescale
      float vmax = fmaxf(lmax, __shfl_xor(lmax, 16));
      vmax = fmaxf(vmax, __shfl_xor(vmax, 32));
      const float mnew = fmaxf(m, vmax);
      const float corr = exp2f(m - mnew);
      m = mnew;
      lp *= corr;
      const float c0 = __shfl(corr, lhi4 + 0);
      const float c1 = __shfl(corr, lhi4 + 1);
      const float c2 = __shfl(corr, lhi4 + 2);
      const float c3 = __shfl(corr, lhi4 + 3);
#pragma unroll
      for (int dt = 0; dt < 4; dt++) {
        o[dt][0] *= c0; o[dt][1] *= c1; o[dt][2] *= c2; o[dt][3] *= c3;
      }
    }
#pragma unroll
    for (int hk = 0; hk < 4; ++hk) {
      const float e0 = exp2f(s[hk][0] - m);
      const float e1 = exp2f(s[hk][1] - m);
      const float e2 = exp2f(s[hk][2] - m);
      const float e3 = exp2f(s[hk][3] - m);
      lp += (e0 + e1) + (e2 + e3);
      const fp16v2 lo2 = __builtin_amdgcn_cvt_pkrtz(e0, e1);
      const fp16v2 hi2 = __builtin_amdgcn_cvt_pkrtz(e2, e3);
      uint2 qw;
      qw.x = __builtin_bit_cast(unsigned int, lo2);
      qw.y = __builtin_bit_cast(unsigned int, hi2);
      *(uint2*)(prb + ((hk * 2 + plhi2) ^ pswz) * 8 + phalf) = qw;
    }

    // ---- V23 + P reads, then single LDS drain -------------------------
    const h16* vr2 = Vc + (32 + l15) * 64;
    const h16* vr3 = Vc + (48 + l15) * 64;
    const f16x8 va2 = *(const f16x8*)(vr2 + x0);
    const f16x8 vb2 = *(const f16x8*)(vr2 + x1);
    const f16x8 va3 = *(const f16x8*)(vr3 + x0);
    const f16x8 vb3 = *(const f16x8*)(vr3 + x1);
    const f16x8 pf0 = *(const f16x8*)(pl + l15 * 64 + x0);
    const f16x8 pf1 = *(const f16x8*)(pl + l15 * 64 + x1);
    asm volatile("s_waitcnt lgkmcnt(0)" ::: "memory");
    __builtin_amdgcn_sched_barrier(0);

    // ---- PV -----------------------------------------------------------
    __builtin_amdgcn_s_setprio(1);
    o[0] = __builtin_amdgcn_mfma_f32_16x16x32_f16(pf0, va0, o[0], 0, 0, 0);
    o[0] = __builtin_amdgcn_mfma_f32_16x16x32_f16(pf1, vb0, o[0], 0, 0, 0);
    o[1] = __builtin_amdgcn_mfma_f32_16x16x32_f16(pf0, va1, o[1], 0, 0, 0);
    o[1] = __builtin_amdgcn_mfma_f32_16x16x32_f16(pf1, vb1, o[1], 0, 0, 0);
    o[2] = __builtin_amdgcn_mfma_f32_16x16x32_f16(pf0, va2, o[2], 0, 0, 0);
    o[2] = __builtin_amdgcn_mfma_f32_16x16x32_f16(pf1, vb2, o[2], 0, 0, 0);
    o[3] = __builtin_amdgcn_mfma_f32_16x16x32_f16(pf0, va3, o[3], 0, 0, 0);
    o[3] = __builtin_amdgcn_mfma_f32_16x16x32_f16(pf1, vb3, o[3], 0, 0, 0);
    __builtin_amdgcn_s_setprio(0);

    cur = (cur == 2) ? 0 : cur + 1;
  }
#undef ASTAGE

  // epilogue: finish denominator (reduce over lhi groups), write out
  float l = lp;
  l += __shfl_xor(l, 16);
  l += __shfl_xor(l, 32);
  const int qg0 = q0 + w * 16 + lhi4;
#pragma unroll
  for (int r = 0; r < 4; r++) {
    const float lr = __shfl(l, lhi4 + r);
    const float inv = 1.0f / lr;
    const size_t row = (size_t)(b * NTOK + qg0 + r);
#pragma unroll
    for (int dt = 0; dt < 4; dt++) {
      const int col = h * 64 + dt * 16 + l15;
      AX[row * CDIM + col] = (h16)(o[dt][r] * inv);
    }
  }
}

// ---------------------------------------------------------------------------
extern "C" void kernel_launch(void* const* d_in, const int* in_sizes, int n_in,
                              void* d_out, int out_size, void* d_ws, size_t ws_size,
                              hipStream_t stream) {
  (void)in_sizes; (void)n_in; (void)out_size; (void)ws_size;
  const float* q  = (const float*)d_in[0];
  const float* kv = (const float*)d_in[1];
  const float* Wq = (const float*)d_in[2];
  const float* bq = (const float*)d_in[3];
  const float* Wk = (const float*)d_in[4];
  const float* bk = (const float*)d_in[5];
  const float* Wv = (const float*)d_in[6];
  const float* bv = (const float*)d_in[7];
  const float* Wo = (const float*)d_in[8];
  const float* bo = (const float*)d_in[9];
  float* out = (float*)d_out;

  char* ws = (char*)d_ws;
  const size_t SZ_MK = (size_t)MROWS * CDIM * sizeof(h16);  // 16 MB
  const size_t SZ_W  = (size_t)CDIM * CDIM * sizeof(h16);   // 2 MB
  h16* qb  = (h16*)(ws);
  h16* kvb = (h16*)(ws + SZ_MK);
  h16* wqt = (h16*)(ws + 2 * SZ_MK);
  h16* wkt = (h16*)(ws + 2 * SZ_MK + SZ_W);
  h16* wvt = (h16*)(ws + 2 * SZ_MK + 2 * SZ_W);
  h16* wot = (h16*)(ws + 2 * SZ_MK + 3 * SZ_W);
  h16* Qh  = (h16*)(ws + 2 * SZ_MK + 4 * SZ_W);
  h16* Kh  = (h16*)(ws + 3 * SZ_MK + 4 * SZ_W);
  h16* VTh = (h16*)(ws + 4 * SZ_MK + 4 * SZ_W);
  h16* ax  = (h16*)(ws);  // overlays qb (qb dead after Q projection)

  cvt_f16<<<4096, 256, 0, stream>>>(q, qb);
  cvt_f16<<<4096, 256, 0, stream>>>(kv, kvb);
  wtrans<<<dim3(32, 32, 4), dim3(32, 8), 0, stream>>>(Wq, Wk, Wv, Wo,
                                                      wqt, wkt, wvt, wot);
  gemm_qkv<<<1536, 256, 0, stream>>>(qb, kvb, wqt, wkt, wvt, bq, bk, bv,
                                     Qh, Kh, VTh);
  attn_kernel<<<2048, 256, 0, stream>>>(Qh, Kh, VTh, ax);
  gemm_out<<<512, 256, 0, stream>>>(ax, wot, bo, out);
}